// Round 11
// baseline (531.186 us; speedup 1.0000x reference)
//
#include <hip/hip_runtime.h>
#include <stdint.h>

// Problem constants
#define TT     48000   // T
#define TK     120     // samples per chunk (T/K)
#define NC     128     // CIN == COUT
#define NA     384     // CIN*KS
#define NZ     64
#define NH     32
#define NK     400
#define NCHUNK 1600    // B*K
#define MW     49152   // CIN*COUT*KS

typedef float f32x4 __attribute__((ext_vector_type(4)));
typedef __bf16 bf16x8 __attribute__((ext_vector_type(8)));

static __device__ __forceinline__ uint16_t f2bf(float f) {
    uint32_t x; __builtin_memcpy(&x, &f, 4);
    return (uint16_t)((x + 0x7fffu + ((x >> 16) & 1u)) >> 16);
}
static __device__ __forceinline__ uint32_t pk2u(uint16_t lo, uint16_t hi) {
    return (uint32_t)lo | ((uint32_t)hi << 16);
}

// ---------------------------------------------------------------------------
// k0w: permute+convert w2 -> w2p bf16 [m'][32], m' = c*384 + a  (m = a*128+c)
//      and b2 -> b2p f32 [m'].  (verbatim from the verified r0-r5 pipeline)
// ---------------------------------------------------------------------------
__global__ __launch_bounds__(256) void k0w(
    const float* __restrict__ w2, const float* __restrict__ b2,
    uint16_t* __restrict__ w2p, float* __restrict__ b2p) {
    int m = blockIdx.x * 256 + threadIdx.x;   // 0..49151
    int a = m >> 7, c = m & 127;
    int mp = c * NA + a;
    const float* src = w2 + (size_t)m * NH;
    uint16_t* dst = w2p + (size_t)mp * NH;
#pragma unroll
    for (int i = 0; i < NH; i += 8) {
        float4 v0 = *(const float4*)(src + i);
        float4 v1 = *(const float4*)(src + i + 4);
        uint4 o;
        o.x = pk2u(f2bf(v0.x), f2bf(v0.y));
        o.y = pk2u(f2bf(v0.z), f2bf(v0.w));
        o.z = pk2u(f2bf(v1.x), f2bf(v1.y));
        o.w = pk2u(f2bf(v1.z), f2bf(v1.w));
        *(uint4*)(dst + i) = o;
    }
    b2p[mp] = b2[m];
}

// ---------------------------------------------------------------------------
// k1: 4 chunks per block (one per wave). Verified, unchanged.
// ---------------------------------------------------------------------------
__global__ __launch_bounds__(256) void k1_hidden(
    const float* __restrict__ z,
    const float* __restrict__ w1, const float* __restrict__ b1,
    const float* __restrict__ bw1, const float* __restrict__ bb1,
    const float* __restrict__ bw2, const float* __restrict__ bb2,
    uint16_t* __restrict__ Hb, float* __restrict__ biasws) {
    int tid = threadIdx.x, lane = tid & 63, w = tid >> 6;
    int chunk0 = blockIdx.x * 4;
    int b = chunk0 / NK;            // 400 % 4 == 0: all 4 chunks same b
    int k0 = chunk0 - b * NK;

    __shared__ float w1sT[64][33];
    __shared__ float bw1sT[64][33];
    __shared__ float bw2s[128][33];
    __shared__ float zs[64][4];
    __shared__ float hbs[4][33];
    __shared__ float b1s[32], bb1s[32], bb2s[128];

    {   // stage w1, bw1 (transposed)
        int row = tid >> 3, c0 = (tid & 7) * 8;
        float4 a0 = *(const float4*)(w1 + row * NZ + c0);
        float4 a1 = *(const float4*)(w1 + row * NZ + c0 + 4);
        float4 c0v = *(const float4*)(bw1 + row * NZ + c0);
        float4 c1v = *(const float4*)(bw1 + row * NZ + c0 + 4);
        const float av[8] = {a0.x,a0.y,a0.z,a0.w,a1.x,a1.y,a1.z,a1.w};
        const float cv[8] = {c0v.x,c0v.y,c0v.z,c0v.w,c1v.x,c1v.y,c1v.z,c1v.w};
#pragma unroll
        for (int j = 0; j < 8; ++j) {
            w1sT[c0 + j][row]  = av[j];
            bw1sT[c0 + j][row] = cv[j];
        }
    }
    {   // stage bw2 [128][32]
        int r = tid >> 1, cb = (tid & 1) * 16;
        float4 v0 = *(const float4*)(bw2 + r * NH + cb);
        float4 v1 = *(const float4*)(bw2 + r * NH + cb + 4);
        float4 v2 = *(const float4*)(bw2 + r * NH + cb + 8);
        float4 v3 = *(const float4*)(bw2 + r * NH + cb + 12);
        const float vv[16] = {v0.x,v0.y,v0.z,v0.w,v1.x,v1.y,v1.z,v1.w,
                              v2.x,v2.y,v2.z,v2.w,v3.x,v3.y,v3.z,v3.w};
#pragma unroll
        for (int j = 0; j < 16; ++j) bw2s[r][cb + j] = vv[j];
    }
    if (tid < 64) {
        float4 zv = *(const float4*)(z + ((size_t)b * NZ + tid) * NK + k0);
        zs[tid][0] = zv.x; zs[tid][1] = zv.y; zs[tid][2] = zv.z; zs[tid][3] = zv.w;
    }
    if (tid < 32) { b1s[tid] = b1[tid]; bb1s[tid] = bb1[tid]; }
    if (tid >= 128 && tid < 256) bb2s[tid - 128] = bb2[tid - 128];
    __syncthreads();

    int chunk = chunk0 + w;
    if (lane < NH) {
        float s = b1s[lane];
#pragma unroll
        for (int i = 0; i < NZ; ++i) s = fmaf(w1sT[i][lane], zs[i][w], s);
        Hb[(size_t)chunk * NH + lane] = f2bf(fmaxf(s, 0.f));
    } else {
        int j = lane - NH;
        float s = bb1s[j];
#pragma unroll
        for (int i = 0; i < NZ; ++i) s = fmaf(bw1sT[i][j], zs[i][w], s);
        hbs[w][j] = fmaxf(s, 0.f);
    }

#pragma unroll
    for (int r = 0; r < 2; ++r) {
        int c = r * 64 + lane;
        float s = bb2s[c];
#pragma unroll
        for (int j = 0; j < NH; ++j) s = fmaf(bw2s[c][j], hbs[w][j], s);
        biasws[(size_t)chunk * NC + c] = s;
    }
}

// ---------------------------------------------------------------------------
// k23: fully fused wgen + conv. Block = 8 chunks x 16 couts (grid 1600,
// 512 thr, 1 block/CU). Deletes the Wt 157 MB write+read round-trip.
//   Phase 1 (wgen): 48 MFMAs/wave build W[8ch][16c][384a] (96 KB) in LDS
//     from L2-resident w2p (k2's exact math; B-cols 8..15 masked).
//     Slot XOR ^(c&7)^(ch&7): write-side ~2-way, read-side matches r6 k3.
//   Phase 2 (conv, x8 chunks): transpose-stage Xa (32 KB, r10's verified
//     reg-split code -> next chunk's x loads fly under this chunk's conv),
//     12 MFMA/wave (wave = 16-t tile x 16 c x 384 a), epilogue.
//   XCD-affine map: cg = (i&7)+8*(i>>6), cog = (i>>3)&7 -> the 8 cout-
//     blocks of a chunk-group land on one XCD; x window HBM-fetched once.
// Same MFMA ops / rounding / a-ascending accumulation -> bit-identical.
// ---------------------------------------------------------------------------
__global__ __launch_bounds__(512) void k23(
    const uint16_t* __restrict__ w2p, const float* __restrict__ b2p,
    const uint16_t* __restrict__ Hb, const float* __restrict__ x,
    const float* __restrict__ biasws, float* __restrict__ out) {
    int i = blockIdx.x;
    int cg  = (i & 7) + 8 * (i >> 6);   // chunk-group 0..199
    int cog = (i >> 3) & 7;             // cout-group 0..7
    int chunk0 = cg * 8;
    int b = chunk0 / NK;                // 8 | 400: all chunks same b
    int k0 = chunk0 - b * NK;
    int c0 = cog * 16;
    int tid = threadIdx.x, lane = tid & 63, w = tid >> 6;   // w 0..7
    int quad = lane >> 4, li = lane & 15;

    __shared__ __align__(16) char Wl[98304];   // [ch 8][c 16][48 slot][16B]
    __shared__ __align__(16) char Xa[32768];   // 128 rows x 256B, swizzled

    const float* xb = x + (size_t)b * NC * TT;
    int thalf = lane >> 5, tq4 = (lane & 31) * 4;

    float4 v0r[4], v1r[4]; float2 u0r[4], u1r[4];
    auto ldreg = [&](int ch) {                 // issue x loads -> regs
        int kb = (k0 + ch) * TK;
#pragma unroll
        for (int ii = 0; ii < 4; ++ii) {
            int cin = (ii * 16 + w * 2 + thalf) * 2;
            int tg = kb + tq4;
            int tga = tg > TT - 4 ? TT - 4 : tg;   // clamp: rows >=122 only
            v0r[ii] = *(const float4*)(xb + (size_t)cin * TT + tga);
            v1r[ii] = *(const float4*)(xb + (size_t)(cin + 1) * TT + tga);
            if (tq4 == 0) {
                if (kb > 0) {
                    u0r[ii] = *(const float2*)(xb + (size_t)cin * TT + kb - 2);
                    u1r[ii] = *(const float2*)(xb + (size_t)(cin + 1) * TT + kb - 2);
                } else {
                    u0r[ii] = make_float2(0.f, 0.f);
                    u1r[ii] = make_float2(0.f, 0.f);
                }
            }
        }
    };
    auto writeXa = [&]() {                     // regs -> swizzled Xa
#pragma unroll
        for (int ii = 0; ii < 4; ++ii) {
            int cin = (ii * 16 + w * 2 + thalf) * 2;
            int q = cin >> 3, wi = (cin & 7) * 2;
            uint32_t pks[4] = { pk2u(f2bf(v0r[ii].x), f2bf(v1r[ii].x)),
                                pk2u(f2bf(v0r[ii].y), f2bf(v1r[ii].y)),
                                pk2u(f2bf(v0r[ii].z), f2bf(v1r[ii].z)),
                                pk2u(f2bf(v0r[ii].w), f2bf(v1r[ii].w)) };
#pragma unroll
            for (int j = 0; j < 4; ++j) {
                int r = tq4 + 2 + j;           // row r holds x[kb + r - 2]
                if (r < 128)
                    *(uint32_t*)(Xa + r * 256 + ((q ^ (r & 15)) << 4) + wi) = pks[j];
            }
            if (tq4 == 0) {                    // rows 0,1: prev tail / zeros
                *(uint32_t*)(Xa + (q << 4) + wi) =
                    pk2u(f2bf(u0r[ii].x), f2bf(u1r[ii].x));
                *(uint32_t*)(Xa + 256 + ((q ^ 1) << 4) + wi) =
                    pk2u(f2bf(u0r[ii].y), f2bf(u1r[ii].y));
            }
        }
    };

    ldreg(0);   // chunk-0 x loads fly under wgen

    // ---- wgen: W slice for this block into Wl
    {
        bf16x8 hfrag = *(const bf16x8*)(Hb + (size_t)(chunk0 + (li & 7)) * NH + quad * 8);
        const uint16_t* wp = w2p + (size_t)c0 * NA * NH;
        const float*    bp = b2p + (size_t)c0 * NA;
#pragma unroll 4
        for (int j = 0; j < 48; ++j) {
            int tj = w * 48 + j;               // m'-tile 0..383
            int cl = tj / 24, a0 = (tj % 24) * 16;
            bf16x8 af = *(const bf16x8*)(wp + (size_t)(tj * 16 + li) * NH + quad * 8);
            f32x4 z4 = {0.f, 0.f, 0.f, 0.f};
            f32x4 d = __builtin_amdgcn_mfma_f32_16x16x32_bf16(af, hfrag, z4, 0, 0, 0);
            float4 bv = *(const float4*)(bp + tj * 16 + quad * 4);
            if (li < 8) {                      // D col = chunk = li (0..7)
                uint16_t p[4] = { f2bf(d[0] + bv.x), f2bf(d[1] + bv.y),
                                  f2bf(d[2] + bv.z), f2bf(d[3] + bv.w) };
                uint64_t pv; __builtin_memcpy(&pv, p, 8);
                int slot = (a0 >> 3) + (quad >> 1);
                *(uint64_t*)(Wl + li * 12288 + cl * 768 +
                             ((slot ^ (cl & 7) ^ (li & 7)) << 4) + (quad & 1) * 8) = pv;
            }
        }
    }
    __syncthreads();   // Wl published; chunk-0 x regs landed

    int tb = w * 16;   // wave's 16-t tile
    for (int ch = 0; ch < 8; ++ch) {
        writeXa();
        if (ch < 7) ldreg(ch + 1);             // overlap next x loads w/ conv
        __syncthreads();                       // Xa(ch) ready

        f32x4 acc = {0.f, 0.f, 0.f, 0.f};
#pragma unroll
        for (int m = 0; m < 12; ++m) {         // a-steps of 32, ascending
            int tap = m >> 2, qb = (m & 3) * 4 + quad;
            int r = tb + li + 2 - tap;
            r = r > 127 ? 127 : r;             // clamped rows feed t>=120 only
            bf16x8 af = *(const bf16x8*)(Xa + r * 256 + ((qb ^ (r & 15)) << 4));
            bf16x8 bf = *(const bf16x8*)(Wl + ch * 12288 + li * 768 +
                         (((m * 4 + quad) ^ (li & 7) ^ (ch & 7)) << 4));
            acc = __builtin_amdgcn_mfma_f32_16x16x32_bf16(af, bf, acc, 0, 0, 0);
        }
        {   // epilogue: D col = c = li, row = t = tb + quad*4 + reg
            int cgl = c0 + li;
            float bias = biasws[(size_t)(chunk0 + ch) * NC + cgl];
            int t0v = tb + quad * 4;
            if (t0v < TK) {
                float* ob = out + ((size_t)b * NC + cgl) * TT + (size_t)(k0 + ch) * TK;
                *(float4*)(ob + t0v) = make_float4(acc[0] + bias, acc[1] + bias,
                                                   acc[2] + bias, acc[3] + bias);
            }
        }
        if (ch < 7) __syncthreads();           // Xa reads done before overwrite
    }
}

// ---------------------------------------------------------------------------
// launch: 3 dispatches, no Wt, no batching loop.
// ---------------------------------------------------------------------------
extern "C" void kernel_launch(void* const* d_in, const int* in_sizes, int n_in,
                              void* d_out, int out_size, void* d_ws, size_t ws_size,
                              hipStream_t stream) {
    const float* x   = (const float*)d_in[0];
    const float* z   = (const float*)d_in[1];
    const float* w1  = (const float*)d_in[2];
    const float* b1  = (const float*)d_in[3];
    const float* w2  = (const float*)d_in[4];
    const float* b2  = (const float*)d_in[5];
    const float* bw1 = (const float*)d_in[6];
    const float* bb1 = (const float*)d_in[7];
    const float* bw2 = (const float*)d_in[8];
    const float* bb2 = (const float*)d_in[9];
    float* out = (float*)d_out;

    // ws layout (all 256-aligned): 4.3 MB total
    char* ws = (char*)d_ws;
    uint16_t* Hb     = (uint16_t*)(ws);                 //   102,400 B
    float*    biasws = (float*)(ws + 102400);           //   819,200 B
    uint16_t* w2p    = (uint16_t*)(ws + 921600);        // 3,145,728 B
    float*    b2p    = (float*)(ws + 4067328);          //   196,608 B

    k0w<<<MW / 256, 256, 0, stream>>>(w2, b2, w2p, b2p);
    k1_hidden<<<NCHUNK / 4, 256, 0, stream>>>(z, w1, b1, bw1, bb1, bw2, bb2, Hb, biasws);
    k23<<<NCHUNK / 8 * 8, 512, 0, stream>>>(w2p, b2p, Hb, x, biasws, out);
}

// Round 12
// 284.704 us; speedup vs baseline: 1.8657x; 1.8657x over previous
//
#include <hip/hip_runtime.h>
#include <stdint.h>

// Problem constants
#define TT     48000   // T
#define TK     120     // samples per chunk (T/K)
#define NC     128     // CIN == COUT
#define NA     384     // CIN*KS
#define NZ     64
#define NH     32
#define NK     400
#define NCHUNK 1600    // B*K
#define MW     49152   // CIN*COUT*KS

typedef float f32x4 __attribute__((ext_vector_type(4)));
typedef __bf16 bf16x8 __attribute__((ext_vector_type(8)));

static __device__ __forceinline__ uint16_t f2bf(float f) {
    uint32_t x; __builtin_memcpy(&x, &f, 4);
    return (uint16_t)((x + 0x7fffu + ((x >> 16) & 1u)) >> 16);
}
static __device__ __forceinline__ uint32_t pk2u(uint16_t lo, uint16_t hi) {
    return (uint32_t)lo | ((uint32_t)hi << 16);
}

// ---------------------------------------------------------------------------
// k1: 4 chunks per block (one per wave). All weights staged in LDS with
// conflict-free layouts; coalesced global loads.
// ---------------------------------------------------------------------------
__global__ __launch_bounds__(256) void k1_hidden(
    const float* __restrict__ z,
    const float* __restrict__ w1, const float* __restrict__ b1,
    const float* __restrict__ bw1, const float* __restrict__ bb1,
    const float* __restrict__ bw2, const float* __restrict__ bb2,
    uint16_t* __restrict__ Hb, float* __restrict__ biasws) {
    int tid = threadIdx.x, lane = tid & 63, w = tid >> 6;
    int chunk0 = blockIdx.x * 4;
    int b = chunk0 / NK;            // 400 % 4 == 0: all 4 chunks same b
    int k0 = chunk0 - b * NK;

    __shared__ float w1sT[64][33];   // [i][h] transposed, conflict-free reads
    __shared__ float bw1sT[64][33];
    __shared__ float bw2s[128][33];  // [c][j]
    __shared__ float zs[64][4];
    __shared__ float hbs[4][33];
    __shared__ float b1s[32], bb1s[32], bb2s[128];

    {   // stage w1, bw1 (transposed)
        int row = tid >> 3, c0 = (tid & 7) * 8;
        float4 a0 = *(const float4*)(w1 + row * NZ + c0);
        float4 a1 = *(const float4*)(w1 + row * NZ + c0 + 4);
        float4 c0v = *(const float4*)(bw1 + row * NZ + c0);
        float4 c1v = *(const float4*)(bw1 + row * NZ + c0 + 4);
        const float av[8] = {a0.x,a0.y,a0.z,a0.w,a1.x,a1.y,a1.z,a1.w};
        const float cv[8] = {c0v.x,c0v.y,c0v.z,c0v.w,c1v.x,c1v.y,c1v.z,c1v.w};
#pragma unroll
        for (int j = 0; j < 8; ++j) {
            w1sT[c0 + j][row]  = av[j];
            bw1sT[c0 + j][row] = cv[j];
        }
    }
    {   // stage bw2 [128][32]
        int r = tid >> 1, cb = (tid & 1) * 16;
        float4 v0 = *(const float4*)(bw2 + r * NH + cb);
        float4 v1 = *(const float4*)(bw2 + r * NH + cb + 4);
        float4 v2 = *(const float4*)(bw2 + r * NH + cb + 8);
        float4 v3 = *(const float4*)(bw2 + r * NH + cb + 12);
        const float vv[16] = {v0.x,v0.y,v0.z,v0.w,v1.x,v1.y,v1.z,v1.w,
                              v2.x,v2.y,v2.z,v2.w,v3.x,v3.y,v3.z,v3.w};
#pragma unroll
        for (int j = 0; j < 16; ++j) bw2s[r][cb + j] = vv[j];
    }
    if (tid < 64) {
        float4 zv = *(const float4*)(z + ((size_t)b * NZ + tid) * NK + k0);
        zs[tid][0] = zv.x; zs[tid][1] = zv.y; zs[tid][2] = zv.z; zs[tid][3] = zv.w;
    }
    if (tid < 32) { b1s[tid] = b1[tid]; bb1s[tid] = bb1[tid]; }
    if (tid >= 128 && tid < 256) bb2s[tid - 128] = bb2[tid - 128];
    __syncthreads();

    int chunk = chunk0 + w;
    if (lane < NH) {
        float s = b1s[lane];
#pragma unroll
        for (int i = 0; i < NZ; ++i) s = fmaf(w1sT[i][lane], zs[i][w], s);
        Hb[(size_t)chunk * NH + lane] = f2bf(fmaxf(s, 0.f));
    } else {
        int j = lane - NH;
        float s = bb1s[j];
#pragma unroll
        for (int i = 0; i < NZ; ++i) s = fmaf(bw1sT[i][j], zs[i][w], s);
        hbs[w][j] = fmaxf(s, 0.f);
    }

#pragma unroll
    for (int r = 0; r < 2; ++r) {
        int c = r * 64 + lane;
        float s = bb2s[c];
#pragma unroll
        for (int j = 0; j < NH; ++j) s = fmaf(bw2s[c][j], hbs[w][j], s);
        biasws[(size_t)chunk * NC + c] = s;
    }
}

// ---------------------------------------------------------------------------
// k2: MFMA weight materialization (k0w fused into prologue; verified r6-r8).
// Block = 256 m' slice; afrag gathered ONCE directly from w2 (permuted
// index m = a*128+c; L2-resident 6.3 MB) and held in registers across a
// 10-group chunk loop. St-LDS readback gives coalesced 128B+ store runs.
// ---------------------------------------------------------------------------
__global__ __launch_bounds__(256) void k2_wgen(
    const float* __restrict__ w2, const float* __restrict__ b2,
    const uint16_t* __restrict__ Hb, uint16_t* __restrict__ Wt,
    int chunk0, int nchunk) {
    int tid = threadIdx.x, lane = tid & 63, w = tid >> 6;
    int quad = lane >> 4, li = lane & 15;
    __shared__ __align__(16) uint16_t St[4][16][68];   // pad 64->68
    int mb = blockIdx.x * 256 + w * 64;                // wave's m' base

    bf16x8 afrag[4];   // loop-invariant A tiles (registers)
    float4 bias[4];
#pragma unroll
    for (int t = 0; t < 4; ++t) {
        int mp = mb + t * 16 + li;                     // m' = c*384 + a
        int a = mp % NA, c = mp / NA;
        const float* src = w2 + ((size_t)a * NC + c) * NH + quad * 8;
        float4 v0 = *(const float4*)(src);
        float4 v1 = *(const float4*)(src + 4);
        uint16_t tmp[8] = { f2bf(v0.x), f2bf(v0.y), f2bf(v0.z), f2bf(v0.w),
                            f2bf(v1.x), f2bf(v1.y), f2bf(v1.z), f2bf(v1.w) };
        __builtin_memcpy(&afrag[t], tmp, 16);
        float bv[4];
#pragma unroll
        for (int r = 0; r < 4; ++r) {
            int mpr = mb + t * 16 + quad * 4 + r;
            bv[r] = b2[(size_t)(mpr % NA) * NC + (mpr / NA)];
        }
        bias[t] = make_float4(bv[0], bv[1], bv[2], bv[3]);
    }

    for (int g = 0; g < 10; ++g) {
        int cl0 = blockIdx.y * 160 + g * 16;           // local chunk base
        if (cl0 >= nchunk) break;
        int cl = cl0 + li;
        if (cl >= nchunk) cl = nchunk - 1;
        bf16x8 hfrag = *(const bf16x8*)(Hb + (size_t)(chunk0 + cl) * NH + quad * 8);
#pragma unroll
        for (int t = 0; t < 4; ++t) {
            f32x4 acc = {0.f, 0.f, 0.f, 0.f};
            acc = __builtin_amdgcn_mfma_f32_16x16x32_bf16(afrag[t], hfrag, acc, 0, 0, 0);
            uint16_t p[4] = { f2bf(acc[0] + bias[t].x), f2bf(acc[1] + bias[t].y),
                              f2bf(acc[2] + bias[t].z), f2bf(acc[3] + bias[t].w) };
            uint64_t pv; __builtin_memcpy(&pv, p, 8);
            *(uint64_t*)&St[w][li][t * 16 + quad * 4] = pv;
        }
        // same-wave readback (compiler inserts lgkmcnt wait) + coalesced store
#pragma unroll
        for (int p = 0; p < 2; ++p) {
            int ch = (lane >> 3) + p * 8, part = lane & 7;
            uint4 v = *(const uint4*)&St[w][ch][part * 8];
            int cg = cl0 + ch;
            if (cg < nchunk)
                *(uint4*)(Wt + (size_t)cg * MW + mb + part * 8) = v;
        }
    }
}

// ---------------------------------------------------------------------------
// k3: per-chunk conv GEMM (verified r8 = 284.5 µs total).
// x-transpose fused into the prologue (no Xt intermediate); W tri-buffer
// in LDS with counted vmcnt; 512 threads / 8 waves; LDS 80 KB.
// ---------------------------------------------------------------------------
__global__ __launch_bounds__(512, 4) void k3_conv(
    const float* __restrict__ x, const uint16_t* __restrict__ Wt,
    const float* __restrict__ biasws, float* __restrict__ out, int chunk0) {
    int cl = blockIdx.x, chunk = chunk0 + cl;
    int b = chunk / NK, k = chunk - b * NK;
    int kbase = k * TK;
    int tid = threadIdx.x, lane = tid & 63, w = tid >> 6;   // w 0..7
    int quad = lane >> 4, li = lane & 15;
    int tblk = (w >> 1) * 32, cblk = (w & 1) * 64;

    __shared__ __align__(16) char smem[81920];
    char* Xa  = smem;             // 128 rows x 256B (cin-unit XOR-swizzled)
    char* Db0 = smem + 32768;     // W tri-buf: [c 128][8 slot^(c&7)][8a] =16KB
    char* Db1 = smem + 49152;
    char* Db2 = smem + 65536;
    const uint16_t* WtC = Wt + (size_t)cl * MW;

    // stage of W for one dk: 16 insts/block (2/wave), each 8x128B source runs
    auto stageD = [&](char* dst, int dks) {
#pragma unroll
        for (int j = 0; j < 2; ++j) {
            int g = (w * 2 + j) * 64 + lane;          // 16B-unit index 0..1023
            int c = g >> 3, sd = g & 7;               // 8 units per c
            int o = sd ^ (c & 7);                     // inverse slot swizzle
            const uint16_t* gsrc = WtC + (size_t)c * NA + dks * 64 + o * 8;
            __builtin_amdgcn_global_load_lds(
                (__attribute__((address_space(1))) void*)gsrc,
                (__attribute__((address_space(3))) void*)(dst + (w * 2 + j) * 1024),
                16, 0, 0);
        }
    };

    // issue W stages first: latency hides under the transpose below
    stageD(Db0, 0);
    stageD(Db1, 1);

    // ---- A-transpose staging: x f32 -> Xa bf16, swizzled (fused k0x)
    const float* xb = x + (size_t)b * NC * TT;
    {
        int thalf = lane >> 5;            // 0..1
        int tq4 = (lane & 31) * 4;        // 0..124
#pragma unroll
        for (int i = 0; i < 4; ++i) {
            int p = i * 16 + w * 2 + thalf;   // cin-pair index 0..63
            int cin = p * 2;
            int tg = kbase + tq4;             // 16B-aligned t base
            int tga = tg > TT - 4 ? TT - 4 : tg;   // clamp: rows >=122 only
            float4 v0 = *(const float4*)(xb + (size_t)cin * TT + tga);
            float4 v1 = *(const float4*)(xb + (size_t)(cin + 1) * TT + tga);
            uint32_t pks[4] = { pk2u(f2bf(v0.x), f2bf(v1.x)),
                                pk2u(f2bf(v0.y), f2bf(v1.y)),
                                pk2u(f2bf(v0.z), f2bf(v1.z)),
                                pk2u(f2bf(v0.w), f2bf(v1.w)) };
            int q = cin >> 3, wi = (cin & 7) * 2;
#pragma unroll
            for (int j = 0; j < 4; ++j) {
                int r = tq4 + 2 + j;          // row r holds x[kbase + r - 2]
                if (r < 128)
                    *(uint32_t*)(Xa + r * 256 + ((q ^ (r & 15)) << 4) + wi) = pks[j];
            }
            if (tq4 == 0) {   // rows 0,1: previous-chunk tail or causal zeros
                uint32_t r0 = 0, r1 = 0;
                if (kbase > 0) {
                    float2 u0 = *(const float2*)(xb + (size_t)cin * TT + kbase - 2);
                    float2 u1 = *(const float2*)(xb + (size_t)(cin + 1) * TT + kbase - 2);
                    r0 = pk2u(f2bf(u0.x), f2bf(u1.x));
                    r1 = pk2u(f2bf(u0.y), f2bf(u1.y));
                }
                *(uint32_t*)(Xa + (q << 4) + wi) = r0;
                *(uint32_t*)(Xa + 256 + ((q ^ 1) << 4) + wi) = r1;
            }
        }
    }
    asm volatile("s_waitcnt lgkmcnt(0)" ::: "memory");   // publish Xa (own wave)

    f32x4 acc[2][4];
#pragma unroll
    for (int i = 0; i < 2; ++i)
#pragma unroll
        for (int j = 0; j < 4; ++j) acc[i][j] = (f32x4){0.f, 0.f, 0.f, 0.f};

#pragma unroll
    for (int dk = 0; dk < 6; ++dk) {
        // wait own D(dk) loads (leave D(dk+1)'s 2 in flight), then barrier:
        // all waves' D(dk) writes + Xa ds_writes visible.
        if (dk < 5) asm volatile("s_waitcnt vmcnt(2)" ::: "memory");
        else        asm volatile("s_waitcnt vmcnt(0)" ::: "memory");
        __builtin_amdgcn_s_barrier();
        __builtin_amdgcn_sched_barrier(0);
        if (dk < 4) {   // issue D(dk+2) into the buffer read at dk-1
            int sel = (dk + 2) % 3;
            stageD(sel == 0 ? Db0 : (sel == 1 ? Db1 : Db2), dk + 2);
        }
        int cs = dk % 3;
        char* cur = cs == 0 ? Db0 : (cs == 1 ? Db1 : Db2);
        int tap = dk >> 1;

        bf16x8 bfr[2][4];
#pragma unroll
        for (int s = 0; s < 2; ++s)
#pragma unroll
            for (int ct = 0; ct < 4; ++ct) {
                int c = cblk + ct * 16 + li;
                bfr[s][ct] = *(const bf16x8*)(cur + c * 128
                             + (((s * 4 + quad) ^ (c & 7)) << 4));
            }
#pragma unroll
        for (int s = 0; s < 2; ++s) {
            bf16x8 af[2];
#pragma unroll
            for (int tt = 0; tt < 2; ++tt) {
                int r = tblk + tt * 16 + li + 2 - tap;
                r = r > 127 ? 127 : r;     // clamped rows feed only discarded t
                int q = (dk & 1) * 8 + s * 4 + quad;
                af[tt] = *(const bf16x8*)(Xa + r * 256 + ((q ^ (r & 15)) << 4));
            }
#pragma unroll
            for (int tt = 0; tt < 2; ++tt)
#pragma unroll
                for (int ct = 0; ct < 4; ++ct)
                    acc[tt][ct] = __builtin_amdgcn_mfma_f32_16x16x32_bf16(
                        af[tt], bfr[s][ct], acc[tt][ct], 0, 0, 0);
        }
    }

    // epilogue: D col = c = lane&15 (+tile), row = t = quad*4+reg (+tile)
#pragma unroll
    for (int ct = 0; ct < 4; ++ct) {
        int c = cblk + ct * 16 + li;
        float bias = biasws[(size_t)chunk * NC + c];
        float* ob = out + ((size_t)b * NC + c) * TT + kbase;
#pragma unroll
        for (int tt = 0; tt < 2; ++tt) {
            int t0v = tblk + tt * 16 + quad * 4;
            if (t0v < TK) {
                f32x4 v = acc[tt][ct];
                *(float4*)(ob + t0v) = make_float4(v[0] + bias, v[1] + bias,
                                                   v[2] + bias, v[3] + bias);
            }
        }
    }
}

// ---------------------------------------------------------------------------
// launch
// ---------------------------------------------------------------------------
extern "C" void kernel_launch(void* const* d_in, const int* in_sizes, int n_in,
                              void* d_out, int out_size, void* d_ws, size_t ws_size,
                              hipStream_t stream) {
    const float* x   = (const float*)d_in[0];
    const float* z   = (const float*)d_in[1];
    const float* w1  = (const float*)d_in[2];
    const float* b1  = (const float*)d_in[3];
    const float* w2  = (const float*)d_in[4];
    const float* b2  = (const float*)d_in[5];
    const float* bw1 = (const float*)d_in[6];
    const float* bb1 = (const float*)d_in[7];
    const float* bw2 = (const float*)d_in[8];
    const float* bb2 = (const float*)d_in[9];
    float* out = (float*)d_out;

    // ws layout (all 256-aligned):
    char* ws = (char*)d_ws;
    uint16_t* Hb     = (uint16_t*)(ws);                 //   102,400 B
    float*    biasws = (float*)(ws + 102400);           //   819,200 B
    const size_t wt_off = 921600;
    uint16_t* Wt     = (uint16_t*)(ws + wt_off);        // slice buffer

    // L3 blocking: 800 chunks -> 78.6 MB Wt slice cycling through 256 MB L3.
    size_t avail = (ws_size > wt_off) ? (ws_size - wt_off) : 0;
    int batch = (int)(avail / ((size_t)MW * 2));
    if (batch > 800) batch = 800;
    if (batch < 1) batch = 1;

    k1_hidden<<<NCHUNK / 4, 256, 0, stream>>>(z, w1, b1, bw1, bb1, bw2, bb2, Hb, biasws);

    for (int c0 = 0; c0 < NCHUNK; c0 += batch) {
        int nc = NCHUNK - c0;
        if (nc > batch) nc = batch;
        dim3 g2(MW / 256, (nc + 159) / 160, 1);
        k2_wgen<<<g2, 256, 0, stream>>>(w2, b2, Hb, Wt, c0, nc);
        k3_conv<<<nc, 512, 0, stream>>>(x, Wt, biasws, out, c0);
    }
}

// Round 13
// 270.216 us; speedup vs baseline: 1.9658x; 1.0536x over previous
//
#include <hip/hip_runtime.h>
#include <stdint.h>

// Problem constants
#define TT     48000   // T
#define TK     120     // samples per chunk (T/K)
#define NC     128     // CIN == COUT
#define NA     384     // CIN*KS
#define NZ     64
#define NH     32
#define NK     400
#define NCHUNK 1600    // B*K
#define MW     49152   // CIN*COUT*KS

typedef float f32x4 __attribute__((ext_vector_type(4)));
typedef __bf16 bf16x8 __attribute__((ext_vector_type(8)));

static __device__ __forceinline__ uint16_t f2bf(float f) {
    uint32_t x; __builtin_memcpy(&x, &f, 4);
    return (uint16_t)((x + 0x7fffu + ((x >> 16) & 1u)) >> 16);
}
static __device__ __forceinline__ uint32_t pk2u(uint16_t lo, uint16_t hi) {
    return (uint32_t)lo | ((uint32_t)hi << 16);
}

// ---------------------------------------------------------------------------
// k0w: permute+convert w2 -> w2p bf16 [m'][32], m' = c*384 + a  (m = a*128+c)
//      and b2 -> b2p f32 [m'].  (verbatim r0-r5; restores k2's coalesced
//      prologue — the r6 "fused k0w" made it a 16KB-stride scatter)
// ---------------------------------------------------------------------------
__global__ __launch_bounds__(256) void k0w(
    const float* __restrict__ w2, const float* __restrict__ b2,
    uint16_t* __restrict__ w2p, float* __restrict__ b2p) {
    int m = blockIdx.x * 256 + threadIdx.x;   // 0..49151
    int a = m >> 7, c = m & 127;
    int mp = c * NA + a;
    const float* src = w2 + (size_t)m * NH;
    uint16_t* dst = w2p + (size_t)mp * NH;
#pragma unroll
    for (int i = 0; i < NH; i += 8) {
        float4 v0 = *(const float4*)(src + i);
        float4 v1 = *(const float4*)(src + i + 4);
        uint4 o;
        o.x = pk2u(f2bf(v0.x), f2bf(v0.y));
        o.y = pk2u(f2bf(v0.z), f2bf(v0.w));
        o.z = pk2u(f2bf(v1.x), f2bf(v1.y));
        o.w = pk2u(f2bf(v1.z), f2bf(v1.w));
        *(uint4*)(dst + i) = o;
    }
    b2p[mp] = b2[m];
}

// ---------------------------------------------------------------------------
// k1: 4 chunks per block (one per wave). Verified, unchanged.
// ---------------------------------------------------------------------------
__global__ __launch_bounds__(256) void k1_hidden(
    const float* __restrict__ z,
    const float* __restrict__ w1, const float* __restrict__ b1,
    const float* __restrict__ bw1, const float* __restrict__ bb1,
    const float* __restrict__ bw2, const float* __restrict__ bb2,
    uint16_t* __restrict__ Hb, float* __restrict__ biasws) {
    int tid = threadIdx.x, lane = tid & 63, w = tid >> 6;
    int chunk0 = blockIdx.x * 4;
    int b = chunk0 / NK;            // 400 % 4 == 0: all 4 chunks same b
    int k0 = chunk0 - b * NK;

    __shared__ float w1sT[64][33];   // [i][h] transposed, conflict-free reads
    __shared__ float bw1sT[64][33];
    __shared__ float bw2s[128][33];  // [c][j]
    __shared__ float zs[64][4];
    __shared__ float hbs[4][33];
    __shared__ float b1s[32], bb1s[32], bb2s[128];

    {   // stage w1, bw1 (transposed)
        int row = tid >> 3, c0 = (tid & 7) * 8;
        float4 a0 = *(const float4*)(w1 + row * NZ + c0);
        float4 a1 = *(const float4*)(w1 + row * NZ + c0 + 4);
        float4 c0v = *(const float4*)(bw1 + row * NZ + c0);
        float4 c1v = *(const float4*)(bw1 + row * NZ + c0 + 4);
        const float av[8] = {a0.x,a0.y,a0.z,a0.w,a1.x,a1.y,a1.z,a1.w};
        const float cv[8] = {c0v.x,c0v.y,c0v.z,c0v.w,c1v.x,c1v.y,c1v.z,c1v.w};
#pragma unroll
        for (int j = 0; j < 8; ++j) {
            w1sT[c0 + j][row]  = av[j];
            bw1sT[c0 + j][row] = cv[j];
        }
    }
    {   // stage bw2 [128][32]
        int r = tid >> 1, cb = (tid & 1) * 16;
        float4 v0 = *(const float4*)(bw2 + r * NH + cb);
        float4 v1 = *(const float4*)(bw2 + r * NH + cb + 4);
        float4 v2 = *(const float4*)(bw2 + r * NH + cb + 8);
        float4 v3 = *(const float4*)(bw2 + r * NH + cb + 12);
        const float vv[16] = {v0.x,v0.y,v0.z,v0.w,v1.x,v1.y,v1.z,v1.w,
                              v2.x,v2.y,v2.z,v2.w,v3.x,v3.y,v3.z,v3.w};
#pragma unroll
        for (int j = 0; j < 16; ++j) bw2s[r][cb + j] = vv[j];
    }
    if (tid < 64) {
        float4 zv = *(const float4*)(z + ((size_t)b * NZ + tid) * NK + k0);
        zs[tid][0] = zv.x; zs[tid][1] = zv.y; zs[tid][2] = zv.z; zs[tid][3] = zv.w;
    }
    if (tid < 32) { b1s[tid] = b1[tid]; bb1s[tid] = bb1[tid]; }
    if (tid >= 128 && tid < 256) bb2s[tid - 128] = bb2[tid - 128];
    __syncthreads();

    int chunk = chunk0 + w;
    if (lane < NH) {
        float s = b1s[lane];
#pragma unroll
        for (int i = 0; i < NZ; ++i) s = fmaf(w1sT[i][lane], zs[i][w], s);
        Hb[(size_t)chunk * NH + lane] = f2bf(fmaxf(s, 0.f));
    } else {
        int j = lane - NH;
        float s = bb1s[j];
#pragma unroll
        for (int i = 0; i < NZ; ++i) s = fmaf(bw1sT[i][j], zs[i][w], s);
        hbs[w][j] = fmaxf(s, 0.f);
    }

#pragma unroll
    for (int r = 0; r < 2; ++r) {
        int c = r * 64 + lane;
        float s = bb2s[c];
#pragma unroll
        for (int j = 0; j < NH; ++j) s = fmaf(bw2s[c][j], hbs[w][j], s);
        biasws[(size_t)chunk * NC + c] = s;
    }
}

// ---------------------------------------------------------------------------
// k2: MFMA weight materialization — r5's verified w2p/b2p version (coalesced
// afrag/bias prologue held in registers across a 10-group chunk loop)
// + 1-deep hfrag prefetch (breaks the serial hload->MFMA->store chain;
// prefetch pattern correctness-verified in r10's k2). St-LDS readback
// gives 128B-contiguous store runs. Bit-identical numerics.
// ---------------------------------------------------------------------------
__global__ __launch_bounds__(256) void k2_wgen(
    const uint16_t* __restrict__ w2p, const float* __restrict__ b2p,
    const uint16_t* __restrict__ Hb, uint16_t* __restrict__ Wt,
    int chunk0, int nchunk) {
    int tid = threadIdx.x, lane = tid & 63, w = tid >> 6;
    int quad = lane >> 4, li = lane & 15;
    __shared__ __align__(16) uint16_t St[4][16][68];   // pad 64->68
    int mb = blockIdx.x * 256 + w * 64;                // wave's m' base

    bf16x8 afrag[4];   // loop-invariant A tiles (registers), coalesced loads
    float4 bias[4];
#pragma unroll
    for (int t = 0; t < 4; ++t) {
        afrag[t] = *(const bf16x8*)(w2p + (size_t)(mb + t * 16 + li) * NH + quad * 8);
        bias[t]  = *(const float4*)(b2p + mb + t * 16 + quad * 4);
    }

    int base = blockIdx.y * 160;
    auto hload = [&](int g) -> bf16x8 {
        int cl = base + g * 16 + li;
        if (cl >= nchunk) cl = nchunk - 1;
        return *(const bf16x8*)(Hb + (size_t)(chunk0 + cl) * NH + quad * 8);
    };

    bf16x8 hcur = hload(0);
    for (int g = 0; g < 10; ++g) {
        int cl0 = base + g * 16;
        if (cl0 >= nchunk) break;
        bf16x8 hnext = hcur;
        if (g < 9 && cl0 + 16 < nchunk) hnext = hload(g + 1);   // prefetch
#pragma unroll
        for (int t = 0; t < 4; ++t) {
            f32x4 acc = {0.f, 0.f, 0.f, 0.f};
            acc = __builtin_amdgcn_mfma_f32_16x16x32_bf16(afrag[t], hcur, acc, 0, 0, 0);
            uint16_t p[4] = { f2bf(acc[0] + bias[t].x), f2bf(acc[1] + bias[t].y),
                              f2bf(acc[2] + bias[t].z), f2bf(acc[3] + bias[t].w) };
            uint64_t pv; __builtin_memcpy(&pv, p, 8);
            *(uint64_t*)&St[w][li][t * 16 + quad * 4] = pv;
        }
        // same-wave readback (compiler inserts lgkmcnt wait) + coalesced store
#pragma unroll
        for (int p = 0; p < 2; ++p) {
            int ch = (lane >> 3) + p * 8, part = lane & 7;
            uint4 v = *(const uint4*)&St[w][ch][part * 8];
            int cg = cl0 + ch;
            if (cg < nchunk)
                *(uint4*)(Wt + (size_t)cg * MW + mb + part * 8) = v;
        }
        hcur = hnext;
    }
}

// ---------------------------------------------------------------------------
// k3: per-chunk conv GEMM (verified r8/r12 = 284.5 µs total). Unchanged.
// x-transpose fused into the prologue (no Xt intermediate); W tri-buffer
// in LDS with counted vmcnt; 512 threads / 8 waves; LDS 80 KB.
// ---------------------------------------------------------------------------
__global__ __launch_bounds__(512, 4) void k3_conv(
    const float* __restrict__ x, const uint16_t* __restrict__ Wt,
    const float* __restrict__ biasws, float* __restrict__ out, int chunk0) {
    int cl = blockIdx.x, chunk = chunk0 + cl;
    int b = chunk / NK, k = chunk - b * NK;
    int kbase = k * TK;
    int tid = threadIdx.x, lane = tid & 63, w = tid >> 6;   // w 0..7
    int quad = lane >> 4, li = lane & 15;
    int tblk = (w >> 1) * 32, cblk = (w & 1) * 64;

    __shared__ __align__(16) char smem[81920];
    char* Xa  = smem;             // 128 rows x 256B (cin-unit XOR-swizzled)
    char* Db0 = smem + 32768;     // W tri-buf: [c 128][8 slot^(c&7)][8a] =16KB
    char* Db1 = smem + 49152;
    char* Db2 = smem + 65536;
    const uint16_t* WtC = Wt + (size_t)cl * MW;

    // stage of W for one dk: 16 insts/block (2/wave), each 8x128B source runs
    auto stageD = [&](char* dst, int dks) {
#pragma unroll
        for (int j = 0; j < 2; ++j) {
            int g = (w * 2 + j) * 64 + lane;          // 16B-unit index 0..1023
            int c = g >> 3, sd = g & 7;               // 8 units per c
            int o = sd ^ (c & 7);                     // inverse slot swizzle
            const uint16_t* gsrc = WtC + (size_t)c * NA + dks * 64 + o * 8;
            __builtin_amdgcn_global_load_lds(
                (__attribute__((address_space(1))) void*)gsrc,
                (__attribute__((address_space(3))) void*)(dst + (w * 2 + j) * 1024),
                16, 0, 0);
        }
    };

    // issue W stages first: latency hides under the transpose below
    stageD(Db0, 0);
    stageD(Db1, 1);

    // ---- A-transpose staging: x f32 -> Xa bf16, swizzled (fused k0x)
    const float* xb = x + (size_t)b * NC * TT;
    {
        int thalf = lane >> 5;            // 0..1
        int tq4 = (lane & 31) * 4;        // 0..124
#pragma unroll
        for (int i = 0; i < 4; ++i) {
            int p = i * 16 + w * 2 + thalf;   // cin-pair index 0..63
            int cin = p * 2;
            int tg = kbase + tq4;             // 16B-aligned t base
            int tga = tg > TT - 4 ? TT - 4 : tg;   // clamp: rows >=122 only
            float4 v0 = *(const float4*)(xb + (size_t)cin * TT + tga);
            float4 v1 = *(const float4*)(xb + (size_t)(cin + 1) * TT + tga);
            uint32_t pks[4] = { pk2u(f2bf(v0.x), f2bf(v1.x)),
                                pk2u(f2bf(v0.y), f2bf(v1.y)),
                                pk2u(f2bf(v0.z), f2bf(v1.z)),
                                pk2u(f2bf(v0.w), f2bf(v1.w)) };
            int q = cin >> 3, wi = (cin & 7) * 2;
#pragma unroll
            for (int j = 0; j < 4; ++j) {
                int r = tq4 + 2 + j;          // row r holds x[kbase + r - 2]
                if (r < 128)
                    *(uint32_t*)(Xa + r * 256 + ((q ^ (r & 15)) << 4) + wi) = pks[j];
            }
            if (tq4 == 0) {   // rows 0,1: previous-chunk tail or causal zeros
                uint32_t r0 = 0, r1 = 0;
                if (kbase > 0) {
                    float2 u0 = *(const float2*)(xb + (size_t)cin * TT + kbase - 2);
                    float2 u1 = *(const float2*)(xb + (size_t)(cin + 1) * TT + kbase - 2);
                    r0 = pk2u(f2bf(u0.x), f2bf(u1.x));
                    r1 = pk2u(f2bf(u0.y), f2bf(u1.y));
                }
                *(uint32_t*)(Xa + (q << 4) + wi) = r0;
                *(uint32_t*)(Xa + 256 + ((q ^ 1) << 4) + wi) = r1;
            }
        }
    }
    asm volatile("s_waitcnt lgkmcnt(0)" ::: "memory");   // publish Xa (own wave)

    f32x4 acc[2][4];
#pragma unroll
    for (int i = 0; i < 2; ++i)
#pragma unroll
        for (int j = 0; j < 4; ++j) acc[i][j] = (f32x4){0.f, 0.f, 0.f, 0.f};

#pragma unroll
    for (int dk = 0; dk < 6; ++dk) {
        // wait own D(dk) loads (leave D(dk+1)'s 2 in flight), then barrier:
        // all waves' D(dk) writes + Xa ds_writes visible.
        if (dk < 5) asm volatile("s_waitcnt vmcnt(2)" ::: "memory");
        else        asm volatile("s_waitcnt vmcnt(0)" ::: "memory");
        __builtin_amdgcn_s_barrier();
        __builtin_amdgcn_sched_barrier(0);
        if (dk < 4) {   // issue D(dk+2) into the buffer read at dk-1
            int sel = (dk + 2) % 3;
            stageD(sel == 0 ? Db0 : (sel == 1 ? Db1 : Db2), dk + 2);
        }
        int cs = dk % 3;
        char* cur = cs == 0 ? Db0 : (cs == 1 ? Db1 : Db2);
        int tap = dk >> 1;

        bf16x8 bfr[2][4];
#pragma unroll
        for (int s = 0; s < 2; ++s)
#pragma unroll
            for (int ct = 0; ct < 4; ++ct) {
                int c = cblk + ct * 16 + li;
                bfr[s][ct] = *(const bf16x8*)(cur + c * 128
                             + (((s * 4 + quad) ^ (c & 7)) << 4));
            }
#pragma unroll
        for (int s = 0; s < 2; ++s) {
            bf16x8 af[2];
#pragma unroll
            for (int tt = 0; tt < 2; ++tt) {
                int r = tblk + tt * 16 + li + 2 - tap;
                r = r > 127 ? 127 : r;     // clamped rows feed only discarded t
                int q = (dk & 1) * 8 + s * 4 + quad;
                af[tt] = *(const bf16x8*)(Xa + r * 256 + ((q ^ (r & 15)) << 4));
            }
#pragma unroll
            for (int tt = 0; tt < 2; ++tt)
#pragma unroll
                for (int ct = 0; ct < 4; ++ct)
                    acc[tt][ct] = __builtin_amdgcn_mfma_f32_16x16x32_bf16(
                        af[tt], bfr[s][ct], acc[tt][ct], 0, 0, 0);
        }
    }

    // epilogue: D col = c = lane&15 (+tile), row = t = quad*4+reg (+tile)
#pragma unroll
    for (int ct = 0; ct < 4; ++ct) {
        int c = cblk + ct * 16 + li;
        float bias = biasws[(size_t)chunk * NC + c];
        float* ob = out + ((size_t)b * NC + c) * TT + kbase;
#pragma unroll
        for (int tt = 0; tt < 2; ++tt) {
            int t0v = tblk + tt * 16 + quad * 4;
            if (t0v < TK) {
                f32x4 v = acc[tt][ct];
                *(float4*)(ob + t0v) = make_float4(v[0] + bias, v[1] + bias,
                                                   v[2] + bias, v[3] + bias);
            }
        }
    }
}

// ---------------------------------------------------------------------------
// launch
// ---------------------------------------------------------------------------
extern "C" void kernel_launch(void* const* d_in, const int* in_sizes, int n_in,
                              void* d_out, int out_size, void* d_ws, size_t ws_size,
                              hipStream_t stream) {
    const float* x   = (const float*)d_in[0];
    const float* z   = (const float*)d_in[1];
    const float* w1  = (const float*)d_in[2];
    const float* b1  = (const float*)d_in[3];
    const float* w2  = (const float*)d_in[4];
    const float* b2  = (const float*)d_in[5];
    const float* bw1 = (const float*)d_in[6];
    const float* bb1 = (const float*)d_in[7];
    const float* bw2 = (const float*)d_in[8];
    const float* bb2 = (const float*)d_in[9];
    float* out = (float*)d_out;

    // ws layout (all 256-aligned):
    char* ws = (char*)d_ws;
    uint16_t* Hb     = (uint16_t*)(ws);                 //   102,400 B
    float*    biasws = (float*)(ws + 102400);           //   819,200 B
    uint16_t* w2p    = (uint16_t*)(ws + 921600);        // 3,145,728 B
    float*    b2p    = (float*)(ws + 4067328);          //   196,608 B
    const size_t wt_off = 4263936;
    uint16_t* Wt     = (uint16_t*)(ws + wt_off);        // slice buffer

    // L3 blocking: 800 chunks -> 78.6 MB Wt slice cycling through 256 MB L3.
    size_t avail = (ws_size > wt_off) ? (ws_size - wt_off) : 0;
    int batch = (int)(avail / ((size_t)MW * 2));
    if (batch > 800) batch = 800;
    if (batch < 1) batch = 1;

    k0w<<<MW / 256, 256, 0, stream>>>(w2, b2, w2p, b2p);
    k1_hidden<<<NCHUNK / 4, 256, 0, stream>>>(z, w1, b1, bw1, bb1, bw2, bb2, Hb, biasws);

    for (int c0 = 0; c0 < NCHUNK; c0 += batch) {
        int nc = NCHUNK - c0;
        if (nc > batch) nc = batch;
        dim3 g2(MW / 256, (nc + 159) / 160, 1);
        k2_wgen<<<g2, 256, 0, stream>>>(w2p, b2p, Hb, Wt, c0, nc);
        k3_conv<<<nc, 512, 0, stream>>>(x, Wt, biasws, out, c0);
    }
}